// Round 11
// baseline (7253.188 us; speedup 1.0000x reference)
//
#include <hip/hip_runtime.h>
#include <hip/hip_fp16.h>

#define GD 256   // grid -- 1 WG per CU
#define BD 1024  // 16 waves/CU

constexpr int TSTEPS = 256;
constexpr int DD = 512;
constexpr int KK4 = 2048;
constexpr int LC = 128;

// ---- ws float offsets ----
constexpr size_t OFF_FLAGS_F = 0;        // 256 flag lines (stride 32 ints)
constexpr size_t OFF_REL_F   = 8192;     // 8 release lines
constexpr size_t OFF_HATTR   = 8448;     // [32][512] f32 hatt exchange (coherent)
constexpr size_t OFF_H16_F   = 28928;    // h16 region base
// ---- h16-unit offsets ----
constexpr size_t HO_X16   = 0;           // [32][256][512] fp16(x)
constexpr size_t HO_ATT   = 4194304;     // [32*128][512] att_ctx fp16
constexpr size_t HO_HRING = 6291456;     // [256][32][512] h ring fp16
constexpr size_t HO_WCTX  = 10485760;    // [32][512] wctx exchange fp16
constexpr size_t HO_PACK  = 10502144;    // [256][13312] per-WG packed weights
constexpr int PACKSZ = 13312;            // 8W+8U+8V cols (kp-major) + 2 Wh cols

typedef _Float16 h16;
typedef _Float16 h2  __attribute__((ext_vector_type(2)));
typedef _Float16 h4v __attribute__((ext_vector_type(4)));
typedef _Float16 h8v __attribute__((ext_vector_type(8)));
union H8  { h8v v; h2 p[4]; };
union H4  { h4v v; h2 p[2]; };
union H2U { h2 h; unsigned u; };
union HSU { h16 h; unsigned short u; };

__device__ __forceinline__ float rcp_fast(float x) { return __builtin_amdgcn_rcpf(x); }
__device__ __forceinline__ float ftanh(float x) {
  float e = __expf(2.0f * x);
  return 1.0f - 2.0f * rcp_fast(e + 1.0f);
}
__device__ __forceinline__ float fsig(float x) { return rcp_fast(1.0f + __expf(-x)); }
__device__ __forceinline__ float fdot2(h2 a, h2 b, float c) {
  return __builtin_amdgcn_fdot2(a, b, c, false);
}

// agent-scope coherent ops (bypass L1/L2, land at MALL; no cache invalidation)
__device__ __forceinline__ float cloadf(const float* p) {
  return __hip_atomic_load(p, __ATOMIC_RELAXED, __HIP_MEMORY_SCOPE_AGENT);
}
__device__ __forceinline__ void cstoref(float* p, float v) {
  __hip_atomic_store(p, v, __ATOMIC_RELAXED, __HIP_MEMORY_SCOPE_AGENT);
}
__device__ __forceinline__ void cstoreu(unsigned* p, unsigned v) {
  __hip_atomic_store(p, v, __ATOMIC_RELAXED, __HIP_MEMORY_SCOPE_AGENT);
}
__device__ __forceinline__ void cstoreu8(unsigned long long* p, unsigned long long v) {
  __hip_atomic_store(p, v, __ATOMIC_RELAXED, __HIP_MEMORY_SCOPE_AGENT);
}
__device__ __forceinline__ unsigned long long cloadu8(const void* p) {
  return __hip_atomic_load((const unsigned long long*)p, __ATOMIC_RELAXED,
                           __HIP_MEMORY_SCOPE_AGENT);
}
__device__ __forceinline__ void cstores(h16* p, h16 v) {
  HSU s; s.h = v;
  __hip_atomic_store((unsigned short*)p, s.u, __ATOMIC_RELAXED,
                     __HIP_MEMORY_SCOPE_AGENT);
}

// grid barrier, no atomic RMW
__device__ __forceinline__ void gsync(int* flags, int* rel, int w, int& gen) {
  __syncthreads();
  gen++;
  const int t = threadIdx.x;
  if (w == 0) {
    if (t < 64) {
      if (t == 0)
        __hip_atomic_store(flags, gen, __ATOMIC_RELAXED, __HIP_MEMORY_SCOPE_AGENT);
      for (;;) {
        int m = gen;
#pragma unroll
        for (int i = 0; i < 4; i++) {
          int v = __hip_atomic_load(flags + (t + i * 64) * 32,
                                    __ATOMIC_RELAXED, __HIP_MEMORY_SCOPE_AGENT);
          m = (v < m) ? v : m;
        }
        if (__all(m >= gen)) break;
      }
      if (t == 0) {
#pragma unroll
        for (int i = 0; i < 8; i++)
          __hip_atomic_store(rel + i * 32, gen, __ATOMIC_RELAXED,
                             __HIP_MEMORY_SCOPE_AGENT);
      }
    }
    asm volatile("" ::: "memory");
  } else {
    if (t == 0) {
      __hip_atomic_store(flags + w * 32, gen, __ATOMIC_RELAXED,
                         __HIP_MEMORY_SCOPE_AGENT);
      const int* r = rel + (w & 7) * 32;
      while (__hip_atomic_load(r, __ATOMIC_RELAXED, __HIP_MEMORY_SCOPE_AGENT) < gen)
        __builtin_amdgcn_s_sleep(1);
    }
    asm volatile("" ::: "memory");
  }
  __syncthreads();
}

// Swizzled LDS staging: row bb (257-dword rows), chunk ch (8 dwords); logical
// dword j stored at slot (j + (ch>>2)) & 7 -> conflict-free for stride-32B
// writers (bank = 8*(ch%4) + rot, injective over 32 lanes) AND row-major readers.
__device__ __forceinline__ void stage8(h16* haux, int bb, int ch, uint4 v0, uint4 v1) {
  unsigned* dw = (unsigned*)haux + bb * 257 + ch * 8;
  const int r = (ch >> 2) & 7;
  dw[(0 + r) & 7] = v0.x; dw[(1 + r) & 7] = v0.y;
  dw[(2 + r) & 7] = v0.z; dw[(3 + r) & 7] = v0.w;
  dw[(4 + r) & 7] = v1.x; dw[(5 + r) & 7] = v1.y;
  dw[(6 + r) & 7] = v1.z; dw[(7 + r) & 7] = v1.w;
}

// 8-col GEMV partial over this thread's 8 k-pairs (chunk s of row b), swizzled.
__device__ __forceinline__ void mac8s(const h16* vec, const h16* P, int s, int b,
                                      float* acc) {
  const unsigned* vdw = (const unsigned*)vec + b * 257 + 8 * s;
  const int r = (s >> 2) & 7;
  const h16* Pp = P + (size_t)(8 * s) * 16;
#pragma unroll
  for (int q = 0; q < 8; q++) {
    H2U hu; hu.u = vdw[(q + r) & 7];
    H8 u0; u0.v = *(const h8v*)(Pp + q * 16);
    H8 u1; u1.v = *(const h8v*)(Pp + q * 16 + 8);
#pragma unroll
    for (int j = 0; j < 4; j++) {
      acc[j]     = fdot2(hu.h, u0.p[j], acc[j]);
      acc[4 + j] = fdot2(hu.h, u1.p[j], acc[4 + j]);
    }
  }
}

__global__ __launch_bounds__(BD, 4) void attn_lstm_persistent(
    const float* __restrict__ x, const float* __restrict__ ctx,
    const float* __restrict__ W, const float* __restrict__ V,
    const float* __restrict__ U, const float* __restrict__ bias,
    const float* __restrict__ Wh, const float* __restrict__ Wc,
    const float* __restrict__ batt, const float* __restrict__ wprj,
    float* __restrict__ out, float* __restrict__ ws) {
  __shared__ __align__(16) unsigned char smem[62400];
  h16*   haux  = (h16*)smem;                    // 32 x 514 h16 = 32896 B
  float* red   = (float*)(smem + 32896);        // 16 x 320 f32 = 20480 B
  float* hUk   = (float*)(smem + 53376);        // [8 c][32 b]
  float* xwk   = (float*)(smem + 54400);        // [2][8 c][32 b]
  float* hattp = (float*)(smem + 56448);        // 512
  float* sexps = (float*)(smem + 58496);        // 128
  float* wprjs = (float*)(smem + 59008);        // 512
  float* pre   = (float*)(smem + 61056);        // [8 c][32 b]
  float* bias8 = (float*)(smem + 62080);        // 8
  float* zinv  = (float*)(smem + 62112);

  const int w = blockIdx.x;
  const int t = threadIdx.x;
  int*   flags = (int*)(ws + OFF_FLAGS_F);
  int*   rel   = (int*)(ws + OFF_REL_F);
  float* hattr = ws + OFF_HATTR;
  h16*   hb    = (h16*)(ws + OFF_H16_F);
  h16*   x16   = hb + HO_X16;
  h16*   att16 = hb + HO_ATT;
  h16*   hring = hb + HO_HRING;
  h16*   wctxr = hb + HO_WCTX;
  h16*   packA = hb + HO_PACK;
  const h16* mypack = packA + (size_t)w * PACKSZ;
  const h16* PW  = mypack;            // x@W cols
  const h16* PU  = mypack + 4096;     // h@U cols
  const h16* PV  = mypack + 8192;     // wctx@V cols
  const h16* PWh = mypack + 12288;    // h@Wh cols (2)
  int gen = 0;

  // XCD-local attention mapping: XCD (w&7) handles b in {4*(w&7)..+3}
  const int b2 = (w & 7) * 4 + (w >> 6);       // batch this WG scores
  const int cs = (w >> 3) & 7;                 // 64-col wctx slice

  float c_reg = 0.f;                  // t<64 own c[b = t&31][2w + (t>>5)]

  // ================= setup =================
  // pack W/U/V/Wh transposed-cooperatively: WG w owns k-pair kp=w (rows 2w,2w+1)
  {
    const int kp = w;
    const float* srcs[3] = {W, U, V};
#pragma unroll
    for (int mat = 0; mat < 3; mat++) {
      const float* s0 = srcs[mat] + (size_t)(2 * kp) * KK4;
      const float* s1 = s0 + KK4;
#pragma unroll
      for (int rep = 0; rep < 2; rep++) {
        int col = t + rep * 1024;
        float v0 = s0[col], v1 = s1[col];
        int wo = (col & 511) >> 1;
        int cc = (col & 1) + ((col >> 9) << 1);
        H2U pu; pu.h = h2{(h16)v0, (h16)v1};
        cstoreu((unsigned*)(packA + (size_t)wo * PACKSZ + mat * 4096 + kp * 16 + cc * 2),
                pu.u);
      }
    }
    if (t < 512) {
      int col = t;
      float v0 = Wh[(size_t)(2 * kp) * DD + col];
      float v1 = Wh[(size_t)(2 * kp + 1) * DD + col];
      int wo = col >> 1, cc = col & 1;
      H2U pu; pu.h = h2{(h16)v0, (h16)v1};
      cstoreu((unsigned*)(packA + (size_t)wo * PACKSZ + 12288 + kp * 4 + cc * 2), pu.u);
    }
  }
  // x16 = fp16(x), WG-sliced linear
  {
    size_t i0 = (size_t)w * 16384 + (size_t)t * 16;
#pragma unroll
    for (int q = 0; q < 4; q++) {
      float4 v = *(const float4*)(x + i0 + q * 4);
      H2U lo; lo.h = h2{(h16)v.x, (h16)v.y};
      H2U hi; hi.h = h2{(h16)v.z, (h16)v.w};
      unsigned long long pk = (unsigned long long)lo.u | ((unsigned long long)hi.u << 32);
      cstoreu8((unsigned long long*)(x16 + i0 + q * 4), pk);
    }
  }
  // att16 = fp16(ctx @ Wc + b_att), 16 rows per WG
  {
    float* fbuf = (float*)smem;                   // 32 KB staging
    const int r0 = w * 16;
#pragma unroll
    for (int i = 0; i < 2; i++) {
      int idx4 = i * BD + t;
      int row = idx4 >> 7, c4 = idx4 & 127;
      ((float4*)fbuf)[idx4] = ((const float4*)(ctx + (size_t)(r0 + row) * DD))[c4];
    }
    __syncthreads();
    const int a0 = t & 511, rh = t >> 9;
    float acc[8];
#pragma unroll
    for (int r = 0; r < 8; r++) acc[r] = 0.f;
    for (int cc = 0; cc < DD; cc++) {
      float wv = Wc[(size_t)cc * DD + a0];
#pragma unroll
      for (int r = 0; r < 8; r++)
        acc[r] += fbuf[(8 * rh + r) * DD + cc] * wv;
    }
    const float ba = batt[a0];
    for (int r = 0; r < 8; r++)
      cstores(att16 + (size_t)(r0 + 8 * rh + r) * DD + a0, (h16)(acc[r] + ba));
    __syncthreads();
  }
  // stage wprj + bias8
  if (t < 512) wprjs[t] = wprj[t];
  if (t < 8) bias8[t] = bias[2 * w + (t & 1) + (t >> 1) * 512];
  gsync(flags, rel, w, gen);

  // xw for step 0
  {
    const int bb = t >> 5, ch = t & 31;
    const uint4* sp = (const uint4*)(x16 + ((size_t)bb * TSTEPS + 0) * DD + ch * 16);
    stage8(haux, bb, ch, sp[0], sp[1]);
    __syncthreads();
    const int b = t & 31, s = t >> 5;
    float acc[8] = {0.f,0.f,0.f,0.f,0.f,0.f,0.f,0.f};
    mac8s(haux, PW, s, b, acc);
#pragma unroll
    for (int c = 0; c < 8; c++) acc[c] += __shfl_xor(acc[c], 32);
    if ((t & 32) == 0) {
      int s2 = t >> 6;
#pragma unroll
      for (int c = 0; c < 8; c++) red[s2 * 256 + c * 32 + b] = acc[c];
    }
    __syncthreads();
    if (t < 256) {
      float sm = 0.f;
#pragma unroll
      for (int j2 = 0; j2 < 16; j2++) sm += red[j2 * 256 + t];
      xwk[t] = sm;
    }
    __syncthreads();
  }

  // ================= recurrence: 3 grid barriers/step =================
  for (int step = 0; step < TSTEPS; step++) {
    // ---- S1: load h_{t-1}; hU (8 cols -> hUk) + hatt (2 cols -> MALL) ----
    {
      const int bb = t >> 5, ch = t & 31;
      uint4 v0 = make_uint4(0,0,0,0), v1 = make_uint4(0,0,0,0);
      if (step > 0) {
        const uint4* sp =
            (const uint4*)(hring + ((size_t)(step - 1) * 32 + bb) * DD + ch * 16);
        v0 = sp[0]; v1 = sp[1];
      }
      stage8(haux, bb, ch, v0, v1);
      __syncthreads();
      const int b = t & 31, s = t >> 5;
      float acc[10];
#pragma unroll
      for (int i = 0; i < 10; i++) acc[i] = 0.f;
      mac8s(haux, PU, s, b, acc);
      {
        const unsigned* vdw = (const unsigned*)haux + b * 257 + 8 * s;
        const int r = (s >> 2) & 7;
        const h16* Pp = PWh + (size_t)(8 * s) * 4;
#pragma unroll
        for (int q = 0; q < 8; q++) {
          H2U hu; hu.u = vdw[(q + r) & 7];
          H4 whv; whv.v = *(const h4v*)(Pp + q * 4);
          acc[8] = fdot2(hu.h, whv.p[0], acc[8]);
          acc[9] = fdot2(hu.h, whv.p[1], acc[9]);
        }
      }
#pragma unroll
      for (int c = 0; c < 10; c++) acc[c] += __shfl_xor(acc[c], 32);
      if ((t & 32) == 0) {
        int s2 = t >> 6;
#pragma unroll
        for (int c = 0; c < 10; c++) red[s2 * 320 + c * 32 + b] = acc[c];
      }
      __syncthreads();
      if (t < 320) {
        float sm = 0.f;
#pragma unroll
        for (int j2 = 0; j2 < 16; j2++) sm += red[j2 * 320 + t];
        int c = t >> 5, bq = t & 31;
        if (c < 8) hUk[c * 32 + bq] = sm;
        else cstoref(hattr + (size_t)bq * DD + 2 * w + (c - 8), sm);
      }
    }
    gsync(flags, rel, w, gen);

    // ---- S2': scores (ALL 128 l for b2, x8 redundant) + softmax + wctx slice;
    //           then xw[step+1] prefetch ----
    {
      if (t < 512) hattp[t] = cloadf(hattr + (size_t)b2 * DD + t);
      __syncthreads();
      {
        const int l = t >> 3, sl = t & 7;
        const h16* arow = att16 + (size_t)(b2 * LC + l) * DD + sl * 64;
        const float* hf = hattp + sl * 64;
        const float* wp = wprjs + sl * 64;
        float p = 0.f;
#pragma unroll
        for (int i = 0; i < 8; i++) {
          H8 av; av.v = *(const h8v*)(arow + i * 8);
          int a8 = i * 8;
          p += ftanh((float)av.v[0] + hf[a8+0]) * wp[a8+0]
             + ftanh((float)av.v[1] + hf[a8+1]) * wp[a8+1]
             + ftanh((float)av.v[2] + hf[a8+2]) * wp[a8+2]
             + ftanh((float)av.v[3] + hf[a8+3]) * wp[a8+3]
             + ftanh((float)av.v[4] + hf[a8+4]) * wp[a8+4]
             + ftanh((float)av.v[5] + hf[a8+5]) * wp[a8+5]
             + ftanh((float)av.v[6] + hf[a8+6]) * wp[a8+6]
             + ftanh((float)av.v[7] + hf[a8+7]) * wp[a8+7];
        }
        p += __shfl_xor(p, 1); p += __shfl_xor(p, 2); p += __shfl_xor(p, 4);
        if (sl == 0) sexps[l] = __expf(p);
      }
      __syncthreads();
      if (t < 64) {
        float z = sexps[t] + sexps[t + 64];
        z += __shfl_xor(z, 32); z += __shfl_xor(z, 16); z += __shfl_xor(z, 8);
        z += __shfl_xor(z, 4);  z += __shfl_xor(z, 2);  z += __shfl_xor(z, 1);
        if (t == 0) *zinv = rcp_fast(z);
      }
      __syncthreads();
      // wctx slice: 64 cols (cs) of batch b2
      {
        const float zi = *zinv;
        const int lsl = t & 15, c = t >> 4;
        float acc = 0.f;
#pragma unroll
        for (int j2 = 0; j2 < 8; j2++) {
          int l = lsl + 16 * j2;
          acc += sexps[l] * ctx[(size_t)(b2 * LC + l) * DD + cs * 64 + c];
        }
        acc += __shfl_xor(acc, 1); acc += __shfl_xor(acc, 2);
        acc += __shfl_xor(acc, 4); acc += __shfl_xor(acc, 8);
        if (lsl == 0)
          cstores(wctxr + (size_t)b2 * DD + cs * 64 + c, (h16)(acc * zi));
      }
      // xw prefetch for step+1
      if (step + 1 < TSTEPS) {
        const int bb = t >> 5, ch = t & 31;
        const uint4* sp =
            (const uint4*)(x16 + ((size_t)bb * TSTEPS + step + 1) * DD + ch * 16);
        uint4 v0 = sp[0], v1 = sp[1];
        stage8(haux, bb, ch, v0, v1);
        __syncthreads();
        const int b = t & 31, s = t >> 5;
        float acc[8] = {0.f,0.f,0.f,0.f,0.f,0.f,0.f,0.f};
        mac8s(haux, PW, s, b, acc);
#pragma unroll
        for (int c = 0; c < 8; c++) acc[c] += __shfl_xor(acc[c], 32);
        if ((t & 32) == 0) {
          int s2 = t >> 6;
#pragma unroll
          for (int c = 0; c < 8; c++) red[s2 * 256 + c * 32 + b] = acc[c];
        }
        __syncthreads();
        if (t < 256) {
          float sm = 0.f;
#pragma unroll
          for (int j2 = 0; j2 < 16; j2++) sm += red[j2 * 256 + t];
          xwk[((step + 1) & 1) * 256 + t] = sm;
        }
      }
    }
    gsync(flags, rel, w, gen);

    // ---- S3: preact = xw + hU + wctx@V + bias; gates; h out ----
    {
      const int bb = t >> 5, ch = t & 31;
      const h16* src = wctxr + (size_t)bb * DD + ch * 16;
      unsigned long long q0 = cloadu8(src),     q1 = cloadu8(src + 4);
      unsigned long long q2 = cloadu8(src + 8), q3 = cloadu8(src + 12);
      uint4 v0 = make_uint4((unsigned)q0, (unsigned)(q0 >> 32),
                            (unsigned)q1, (unsigned)(q1 >> 32));
      uint4 v1 = make_uint4((unsigned)q2, (unsigned)(q2 >> 32),
                            (unsigned)q3, (unsigned)(q3 >> 32));
      stage8(haux, bb, ch, v0, v1);
      __syncthreads();
      const int b = t & 31, s = t >> 5;
      float acc[8] = {0.f,0.f,0.f,0.f,0.f,0.f,0.f,0.f};
      mac8s(haux, PV, s, b, acc);
#pragma unroll
      for (int c = 0; c < 8; c++) acc[c] += __shfl_xor(acc[c], 32);
      if ((t & 32) == 0) {
        int s2 = t >> 6;
#pragma unroll
        for (int c = 0; c < 8; c++) red[s2 * 256 + c * 32 + b] = acc[c];
      }
      __syncthreads();
      if (t < 256) {
        float sm = 0.f;
#pragma unroll
        for (int j2 = 0; j2 < 16; j2++) sm += red[j2 * 256 + t];
        int c = t >> 5;
        pre[t] = sm + hUk[t] + xwk[(step & 1) * 256 + t] + bias8[c];
      }
      __syncthreads();
      if (t < 64) {
        const int b3 = t & 31, dd = t >> 5;
        float pi = pre[(0 + dd) * 32 + b3];
        float pf = pre[(2 + dd) * 32 + b3];
        float po = pre[(4 + dd) * 32 + b3];
        float pg = pre[(6 + dd) * 32 + b3];
        float ig = fsig(pi), fg = fsig(pf), og = fsig(po), gg = ftanh(pg);
        float cn = fg * c_reg + ig * gg;
        c_reg = cn;
        float hn = og * ftanh(cn);
        out[((size_t)b3 * TSTEPS + step) * DD + 2 * w + dd] = hn;
        float hn2 = __shfl_xor(hn, 32);
        if (t < 32) {
          H2U pu; pu.h = h2{(h16)hn, (h16)hn2};
          cstoreu((unsigned*)(hring + ((size_t)step * 32 + b3) * DD + 2 * w), pu.u);
        }
      }
    }
    gsync(flags, rel, w, gen);
  }
}

extern "C" void kernel_launch(void* const* d_in, const int* in_sizes, int n_in,
                              void* d_out, int out_size, void* d_ws, size_t ws_size,
                              hipStream_t stream) {
  (void)in_sizes; (void)n_in; (void)out_size; (void)ws_size;
  const float* x    = (const float*)d_in[0];
  const float* ctx  = (const float*)d_in[1];
  const float* W    = (const float*)d_in[2];
  const float* V    = (const float*)d_in[3];
  const float* U    = (const float*)d_in[4];
  const float* b    = (const float*)d_in[5];
  const float* Wh   = (const float*)d_in[6];
  const float* Wc   = (const float*)d_in[7];
  const float* batt = (const float*)d_in[8];
  const float* wprj = (const float*)d_in[9];

  hipMemsetAsync(d_ws, 0, (8192 + 256) * sizeof(int), stream);

  hipLaunchKernelGGL(attn_lstm_persistent, dim3(GD), dim3(BD), 0, stream,
                     x, ctx, W, V, U, b, Wh, Wc, batt, wprj,
                     (float*)d_out, (float*)d_ws);
}